// Round 2
// 1705.589 us; speedup vs baseline: 1.0235x; 1.0235x over previous
//
#include <hip/hip_runtime.h>

// Chambolle-Pock ROF, 20 iterations, 4096x4096 — TWO iterations fused per
// launch (10 launches total, no prep kernels).
//
// Per block: output tile T = 16 rows x 128 cols. LDS holds the halo'd
// intermediates over B2 = 20 rows x 144 cols (tile-local rows -2..17,
// cols -8..135, 8-aligned strips):
//   sXT (f32): xt_t, overwritten by xt_{t+1}   (f32 => no extra rounding
//              in the sigma*grad path; x/y are rounded to half exactly
//              where the unfused pipeline rounded them)
//   sX  (h16): x_t, overwritten by x_{t+1}
//   sY0/sY1 (h16): y'_{t+1}, overwritten in place by y''_{t+2}
// Stages (syncthreads between): load/xt -> y' (rows -2..16) ->
// x_{t+1}/xt_{t+1} (rows -1..16) -> y'' (rows -1..15, cols -1..127) ->
// x_{t+2} on T. w/img/y_t are read straight from global (halo re-reads hit
// L1/L2). First launch reads f32 w/img/y0 and emits w_h/img_h tiles as a
// side effect; last launch writes only the f32 x_tilde output.

#define MM 4096
#define NN 4096
static constexpr size_t PP = (size_t)MM * NN;

static constexpr float SIGMA_F  = 14.285714285714286f;  // 1/(7*0.01)
static constexpr float TAU_F    = 0.01f;
static constexpr float THETA_F  = 0.5f;
static constexpr float LT_F     = 0.07f;                // LAMBDA_ROF * TAU
static constexpr float INV_DEN  = 1.0f / 1.07f;

typedef _Float16 h16;
typedef __attribute__((ext_vector_type(8))) _Float16 h16x8;
typedef __attribute__((ext_vector_type(4))) float f32x4;

#define TR 16       // output tile rows
#define TC 128      // output tile cols
#define BR 20       // LDS rows: tile-local -2..17
#define NSTRIP 18   // 8-wide col strips: cols -8..135
#define LSW 152     // LDS row stride (elements), padded

__device__ __forceinline__ float clip1(float v) {
    return fminf(1.0f, fmaxf(-1.0f, v));
}

template<bool H>
__device__ __forceinline__ void gld8(const void* __restrict__ p, long idx, bool ok, float* o) {
    if (!ok) {
        #pragma unroll
        for (int e = 0; e < 8; ++e) o[e] = 0.f;
        return;
    }
    if constexpr (H) {
        h16x8 v = *reinterpret_cast<const h16x8*>(reinterpret_cast<const h16*>(p) + idx);
        #pragma unroll
        for (int e = 0; e < 8; ++e) o[e] = (float)v[e];
    } else {
        const float* q = reinterpret_cast<const float*>(p) + idx;
        f32x4 a = *reinterpret_cast<const f32x4*>(q);
        f32x4 b = *reinterpret_cast<const f32x4*>(q + 4);
        o[0]=a.x;o[1]=a.y;o[2]=a.z;o[3]=a.w;o[4]=b.x;o[5]=b.y;o[6]=b.z;o[7]=b.w;
    }
}

template<bool H>
__device__ __forceinline__ float gld1(const void* __restrict__ p, long idx, bool ok) {
    if (!ok) return 0.f;
    if constexpr (H) return (float)reinterpret_cast<const h16*>(p)[idx];
    else             return reinterpret_cast<const float*>(p)[idx];
}

__device__ __forceinline__ void lds8h(const h16* p, float* o) {
    h16x8 v = *reinterpret_cast<const h16x8*>(p);
    #pragma unroll
    for (int e = 0; e < 8; ++e) o[e] = (float)v[e];
}
__device__ __forceinline__ void lds8f(const float* p, float* o) {
    f32x4 a = *reinterpret_cast<const f32x4*>(p);
    f32x4 b = *reinterpret_cast<const f32x4*>(p + 4);
    o[0]=a.x;o[1]=a.y;o[2]=a.z;o[3]=a.w;o[4]=b.x;o[5]=b.y;o[6]=b.z;o[7]=b.w;
}

// MODE: 0 = first (xp/xc = img f32, y = f32, w/img = f32; may emit w_h/img_h)
//       1 = mid   2 = last (writes only f32 out)
template<int MODE, bool WH, bool IH>
__global__ __launch_bounds__(256, 4)
void pd2(const h16* __restrict__ xprev, const h16* __restrict__ xcur,
         const void* __restrict__ yin, const void* __restrict__ w,
         const void* __restrict__ img,
         h16* __restrict__ xo1, h16* __restrict__ xo2, h16* __restrict__ yo,
         h16* __restrict__ w_h, h16* __restrict__ img_h,
         float* __restrict__ out)
{
    constexpr bool FIRST = (MODE == 0);
    constexpr bool LAST  = (MODE == 2);
    constexpr bool WRH = (!FIRST) && WH;   // w reads are half
    constexpr bool IRH = (!FIRST) && IH;   // img reads are half

    __shared__ float sXT[BR][LSW];
    __shared__ h16   sX [BR][LSW];
    __shared__ h16   sY0[BR][LSW];
    __shared__ h16   sY1[BR][LSW];

    const int tid = threadIdx.x;
    const int bi0 = blockIdx.y * TR;
    const int bj0 = blockIdx.x * TC;

    // ---------------- Stage 0: xt_t (f32) and x_t (h16) into LDS over B2
    for (int t = tid; t < BR * NSTRIP; t += 256) {
        const int r = t / NSTRIP, s = t - r * NSTRIP;
        const int gi = bi0 - 2 + r;
        const int gj = bj0 - 8 + 8 * s;
        const long idx = (long)gi * NN + gj;
        const bool ok = (gi >= 0) & (gi < MM) & (gj >= 0) & (gj < NN);
        const int l = 8 * s;
        float xt8[8]; h16x8 xh;
        if constexpr (FIRST) {
            float v[8];
            gld8<false>(img, idx, ok, v);            // x0 = x_{-1} = img
            #pragma unroll
            for (int e = 0; e < 8; ++e) { xt8[e] = v[e]; xh[e] = (h16)v[e]; }
        } else {
            float xp[8], xc[8];
            gld8<true>(xprev, idx, ok, xp);
            gld8<true>(xcur,  idx, ok, xc);
            #pragma unroll
            for (int e = 0; e < 8; ++e) {
                xt8[e] = fmaf(THETA_F, xc[e] - xp[e], xc[e]);
                xh[e]  = (h16)xc[e];                 // exact roundtrip
            }
        }
        #pragma unroll
        for (int e = 0; e < 8; ++e) sXT[r][l + e] = xt8[e];
        *reinterpret_cast<h16x8*>(&sX[r][l]) = xh;
    }
    __syncthreads();

    // ---------------- Stage 1a: y'_{t+1} over rows r=0..18, strips 0..17
    for (int t = tid; t < 19 * NSTRIP; t += 256) {
        const int r = t / NSTRIP, s = t - r * NSTRIP;
        const int gi = bi0 - 2 + r;
        const int gj0 = bj0 - 8 + 8 * s;
        const long idx = (long)gi * NN + gj0;
        const bool ok = (gi >= 0) & (gi < MM) & (gj0 >= 0) & (gj0 < NN);
        const int l = 8 * s;

        float y0v[8], y1v[8], w0v[8], w1v[8];
        gld8<!FIRST>(yin, idx, ok, y0v);
        gld8<!FIRST>(yin, (long)PP + idx, ok, y1v);
        gld8<WRH>(w, idx, ok, w0v);
        gld8<WRH>(w, (long)PP + idx, ok, w1v);

        float xtC[8], xtD[8];
        lds8f(&sXT[r][l], xtC);
        const float xtR = sXT[r][l + 8];
        lds8f(&sXT[r + 1][l], xtD);

        h16x8 y0s, y1s;
        #pragma unroll
        for (int e = 0; e < 8; ++e) {
            const int gj = gj0 + e;
            const float xtr = (e < 7) ? xtC[e + 1] : xtR;
            const float gx = (gj < NN - 1) ? (xtr - xtC[e]) : 0.f;
            const float gy = (gi < MM - 1) ? (xtD[e] - xtC[e]) : 0.f;
            y0s[e] = (h16)clip1(fmaf(SIGMA_F * gx, w0v[e], y0v[e]));
            y1s[e] = (h16)clip1(fmaf(SIGMA_F * gy, w1v[e], y1v[e]));
        }
        *reinterpret_cast<h16x8*>(&sY0[r][l]) = y0s;
        *reinterpret_cast<h16x8*>(&sY1[r][l]) = y1s;

        if constexpr (FIRST && WH) {
            if (r >= 2 && r <= 17 && s >= 1 && s <= 16) {   // in T
                h16x8 a, b;
                #pragma unroll
                for (int e = 0; e < 8; ++e) { a[e] = (h16)w0v[e]; b[e] = (h16)w1v[e]; }
                *reinterpret_cast<h16x8*>(&w_h[idx]) = a;
                *reinterpret_cast<h16x8*>(&w_h[PP + idx]) = b;
            }
        }
    }
    __syncthreads();

    // ---------------- Stage 1b: x_{t+1} (h16, in sX) and xt_{t+1} (f32, in
    // sXT) over rows r=1..18, strips 0..17. Only own-strip LDS is written.
    for (int t = tid; t < 18 * NSTRIP; t += 256) {
        const int r = 1 + t / NSTRIP, s = t % NSTRIP;
        const int gi = bi0 - 2 + r;
        const int gj0 = bj0 - 8 + 8 * s;
        const long idx = (long)gi * NN + gj0;
        const bool ok  = (gi >= 0) & (gi < MM) & (gj0 >= 0) & (gj0 < NN);
        const bool okU = (gi >= 1) & (gj0 >= 0) & (gj0 < NN);
        const int l = 8 * s;

        float y0C[8], y1C[8], y1U[8];
        lds8h(&sY0[r][l], y0C);
        lds8h(&sY1[r][l], y1C);
        lds8h(&sY1[r - 1][l], y1U);
        const int lm1 = (l > 0) ? (l - 1) : 0;   // s=0 elem0 is never consumed
        const float y0L = (float)sY0[r][lm1];

        float w0C[8], w1C[8], w1U[8];
        gld8<WRH>(w, idx, ok, w0C);
        gld8<WRH>(w, (long)PP + idx, ok, w1C);
        gld8<WRH>(w, (long)PP + idx - NN, okU, w1U);
        const float w0L = gld1<WRH>(w, idx - 1, ok & (gj0 > 0));

        float gim[8];
        gld8<IRH>(img, idx, ok, gim);   // FIRST => IRH==false => f32 img

        float xc[8];
        if constexpr (FIRST) {
            #pragma unroll
            for (int e = 0; e < 8; ++e) xc[e] = gim[e];   // x_0 = img, f32 exact
        } else {
            lds8h(&sX[r][l], xc);
        }

        float h[8];
        #pragma unroll
        for (int e = 0; e < 8; ++e) {
            const int gj = gj0 + e;
            h[e] = (gj < NN - 1) ? w0C[e] * y0C[e] : 0.f;
        }
        const float hL = w0L * y0L;
        float dh[8];
        dh[0] = h[0] - hL;
        #pragma unroll
        for (int e = 1; e < 8; ++e) dh[e] = h[e] - h[e - 1];

        const bool notbot = (gi < MM - 1);
        h16x8 xh; float xt1[8];
        #pragma unroll
        for (int e = 0; e < 8; ++e) {
            const float vC = notbot ? w1C[e] * y1C[e] : 0.f;
            const float vU = w1U[e] * y1U[e];
            const float xv = (xc[e] + TAU_F * (dh[e] + vC - vU) + LT_F * gim[e]) * INV_DEN;
            const h16 hh = (h16)xv;
            const float xvh = (float)hh;     // half-rounded, as the unfused pipeline sees it
            xh[e] = hh;
            xt1[e] = fmaf(THETA_F, xvh - xc[e], xvh);
        }
        *reinterpret_cast<h16x8*>(&sX[r][l]) = xh;     // x_t -> x_{t+1}
        #pragma unroll
        for (int e = 0; e < 8; ++e) sXT[r][l + e] = xt1[e];  // xt_t -> xt_{t+1}

        if constexpr (!LAST) {
            if (r >= 2 && r <= 17 && s >= 1 && s <= 16)
                *reinterpret_cast<h16x8*>(&xo1[idx]) = xh;
        }
        if constexpr (FIRST && IH) {
            if (r >= 2 && r <= 17 && s >= 1 && s <= 16) {
                h16x8 g8;
                #pragma unroll
                for (int e = 0; e < 8; ++e) g8[e] = (h16)gim[e];
                *reinterpret_cast<h16x8*>(&img_h[idx]) = g8;
            }
        }
    }
    __syncthreads();

    // ---------------- Stage 2a: y''_{t+2} over rows r=1..17, strips 0..16
    // (tile rows -1..15, cols -1..127); in-place over sY0/sY1.
    for (int t = tid; t < 17 * 17; t += 256) {
        const int r = 1 + t / 17, s = t % 17;
        const int gi = bi0 - 2 + r;
        const int gj0 = bj0 - 8 + 8 * s;
        const long idx = (long)gi * NN + gj0;
        const bool ok = (gi >= 0) & (gi < MM) & (gj0 >= 0) & (gj0 < NN);
        const int l = 8 * s;

        float w0v[8], w1v[8];
        gld8<WRH>(w, idx, ok, w0v);
        gld8<WRH>(w, (long)PP + idx, ok, w1v);

        float xtC[8], xtD[8];
        lds8f(&sXT[r][l], xtC);
        const float xtR = sXT[r][l + 8];
        lds8f(&sXT[r + 1][l], xtD);

        float y0p[8], y1p[8];
        lds8h(&sY0[r][l], y0p);
        lds8h(&sY1[r][l], y1p);

        h16x8 y0s, y1s;
        #pragma unroll
        for (int e = 0; e < 8; ++e) {
            const int gj = gj0 + e;
            const float xtr = (e < 7) ? xtC[e + 1] : xtR;
            const float gx = (gj < NN - 1) ? (xtr - xtC[e]) : 0.f;
            const float gy = (gi < MM - 1) ? (xtD[e] - xtC[e]) : 0.f;
            y0s[e] = (h16)clip1(fmaf(SIGMA_F * gx, w0v[e], y0p[e]));
            y1s[e] = (h16)clip1(fmaf(SIGMA_F * gy, w1v[e], y1p[e]));
        }
        *reinterpret_cast<h16x8*>(&sY0[r][l]) = y0s;
        *reinterpret_cast<h16x8*>(&sY1[r][l]) = y1s;
        if constexpr (!LAST) {
            if (r >= 2 && s >= 1) {     // r<=17, s<=16 always hold here
                *reinterpret_cast<h16x8*>(&yo[idx]) = y0s;
                *reinterpret_cast<h16x8*>(&yo[PP + idx]) = y1s;
            }
        }
    }
    __syncthreads();

    // ---------------- Stage 2b: x_{t+2} over T (one task per thread)
    {
        const int r = 2 + (tid >> 4);
        const int s = 1 + (tid & 15);
        const int gi = bi0 - 2 + r;
        const int gj0 = bj0 - 8 + 8 * s;
        const long idx = (long)gi * NN + gj0;
        const int l = 8 * s;

        float y0C[8], y1C[8], y1U[8];
        lds8h(&sY0[r][l], y0C);
        lds8h(&sY1[r][l], y1C);
        lds8h(&sY1[r - 1][l], y1U);
        const float y0L = (float)sY0[r][l - 1];

        float w0C[8], w1C[8], w1U[8];
        gld8<WRH>(w, idx, true, w0C);
        gld8<WRH>(w, (long)PP + idx, true, w1C);
        gld8<WRH>(w, (long)PP + idx - NN, gi > 0, w1U);
        const float w0L = gld1<WRH>(w, idx - 1, gj0 > 0);

        float gim[8];
        gld8<IRH>(img, idx, true, gim);

        float xc1[8];
        lds8h(&sX[r][l], xc1);     // x_{t+1}, half — matches unfused rounding

        float h[8];
        #pragma unroll
        for (int e = 0; e < 8; ++e) {
            const int gj = gj0 + e;
            h[e] = (gj < NN - 1) ? w0C[e] * y0C[e] : 0.f;
        }
        const float hL = w0L * y0L;
        float dh[8];
        dh[0] = h[0] - hL;
        #pragma unroll
        for (int e = 1; e < 8; ++e) dh[e] = h[e] - h[e - 1];

        const bool notbot = (gi < MM - 1);
        if constexpr (!LAST) {
            h16x8 xh;
            #pragma unroll
            for (int e = 0; e < 8; ++e) {
                const float vC = notbot ? w1C[e] * y1C[e] : 0.f;
                const float vU = w1U[e] * y1U[e];
                const float xv = (xc1[e] + TAU_F * (dh[e] + vC - vU) + LT_F * gim[e]) * INV_DEN;
                xh[e] = (h16)xv;
            }
            *reinterpret_cast<h16x8*>(&xo2[idx]) = xh;
        } else {
            float o[8];
            #pragma unroll
            for (int e = 0; e < 8; ++e) {
                const float vC = notbot ? w1C[e] * y1C[e] : 0.f;
                const float vU = w1U[e] * y1U[e];
                const float xv = (xc1[e] + TAU_F * (dh[e] + vC - vU) + LT_F * gim[e]) * INV_DEN;
                o[e] = fmaf(THETA_F, xv - xc1[e], xv);     // x_tilde_20, f32
            }
            f32x4 a, b;
            a.x = o[0]; a.y = o[1]; a.z = o[2]; a.w = o[3];
            b.x = o[4]; b.y = o[5]; b.z = o[6]; b.w = o[7];
            *reinterpret_cast<f32x4*>(&out[idx]) = a;
            *reinterpret_cast<f32x4*>(&out[idx + 4]) = b;
        }
    }
}

template<bool WH, bool IH>
static void run_seq(hipStream_t s, const float* img, const float* w, const float* y0,
                    h16* const* xb, h16* yA, h16* yB, h16* w_h, h16* img_h, float* out)
{
    const dim3 grid(NN / TC, MM / TR);
    const dim3 block(256);
    for (int k = 0; k < 10; ++k) {
        const h16* xp = xb[(2 * k + 3) & 3];
        const h16* xc = xb[(2 * k) & 3];
        h16* xo1 = xb[(2 * k + 1) & 3];
        h16* xo2 = xb[(2 * k + 2) & 3];
        const void* yin = (k == 0) ? (const void*)y0
                                   : ((k & 1) ? (const void*)yA : (const void*)yB);
        h16* yo = (k & 1) ? yB : yA;
        const void* wp = (k == 0) ? (const void*)w
                                  : (WH ? (const void*)w_h : (const void*)w);
        const void* ip = (k == 0) ? (const void*)img
                                  : (IH ? (const void*)img_h : (const void*)img);
        if (k == 0)
            pd2<0, WH, IH><<<grid, block, 0, s>>>(xp, xc, yin, wp, ip, xo1, xo2, yo, w_h, img_h, out);
        else if (k == 9)
            pd2<2, WH, IH><<<grid, block, 0, s>>>(xp, xc, yin, wp, ip, xo1, xo2, yo, w_h, img_h, out);
        else
            pd2<1, WH, IH><<<grid, block, 0, s>>>(xp, xc, yin, wp, ip, xo1, xo2, yo, w_h, img_h, out);
    }
}

extern "C" void kernel_launch(void* const* d_in, const int* in_sizes, int n_in,
                              void* d_out, int out_size, void* d_ws, size_t ws_size,
                              hipStream_t stream) {
    const float* img = (const float*)d_in[0];   // [1,M,N]
    const float* w   = (const float*)d_in[1];   // [2,M,N]
    const float* y0  = (const float*)d_in[2];   // [2,M,N]

    h16* base = (h16*)d_ws;
    h16* xb[4] = { base, base + PP, base + 2 * PP, base + 3 * PP };
    h16* yA = base + 4 * PP;                    // 2 planes

    const size_t planes = ws_size / (PP * sizeof(h16));
    const bool WH = planes >= 8;                          // w as half (2 planes)
    const bool IH = (planes >= 9) || (planes == 7);       // img as half (1 plane)
    h16* w_h   = WH ? base + 6 * PP : nullptr;
    h16* img_h = IH ? (WH ? base + 8 * PP : base + 6 * PP) : nullptr;

    h16* yB = (h16*)d_out;                      // 2 half planes == out_size f32 bytes
    float* out = (float*)d_out;

    if (WH && IH)      run_seq<true,  true >(stream, img, w, y0, xb, yA, yB, w_h, img_h, out);
    else if (WH)       run_seq<true,  false>(stream, img, w, y0, xb, yA, yB, w_h, img_h, out);
    else if (IH)       run_seq<false, true >(stream, img, w, y0, xb, yA, yB, w_h, img_h, out);
    else               run_seq<false, false>(stream, img, w, y0, xb, yA, yB, w_h, img_h, out);
}

// Round 3
// 1535.055 us; speedup vs baseline: 1.1372x; 1.1111x over previous
//
#include <hip/hip_runtime.h>

// Chambolle-Pock ROF, 20 iterations, 4096x4096 — TWO iterations fused per
// launch, ONE strip per thread, register-resident state.
//
// Block: 320 threads = 20 rows x 16 strips (8 px). Region 20x128 around a
// 16x112 interior tile. Each thread loads x_prev/x_cur/y/w/img for its strip
// ONCE (stage 0, all independent -> single latency exposure), keeps them in
// registers across both fused iterations. LDS carries only neighbor data:
//   sXT (f32): x_tilde (t, then t+1)        sY0/sY1 (h16): y' then y''
//   sW0/sW1 (h16): w (for up/left halo access)
// Stages: S0 load+xt -> S1 y'(r<=18) -> S2 x_{t+1}/xt_{t+1}(r=1..18) ->
// S3 y''(r=1..17) -> S4 x_{t+2}(interior). Rounding identical to the
// unfused pipeline: x,y h16-roundtripped at each level, xt kept f32.
// Col index c in [-8,136) maps to LDS index c+8 (16B-aligned strips);
// pads zeroed so halo garbage is bounded (and never reaches the interior).

#define MM 4096
#define NN 4096
static constexpr size_t PP = (size_t)MM * NN;

static constexpr float SIGMA_F  = 14.285714285714286f;  // 1/(7*0.01)
static constexpr float TAU_F    = 0.01f;
static constexpr float THETA_F  = 0.5f;
static constexpr float LT_F     = 0.07f;                // LAMBDA_ROF * TAU
static constexpr float INV_DEN  = 1.0f / 1.07f;

typedef _Float16 h16;
typedef __attribute__((ext_vector_type(8))) _Float16 h16x8;
typedef __attribute__((ext_vector_type(4))) float f32x4;

#define TIR 16      // interior rows per block
#define TIC 112     // interior cols per block
#define RRW 20      // region rows (tile-local -2..17)
#define LSW 144     // LDS row stride: 8 pad + 128 + 8 pad

__device__ __forceinline__ float clip1(float v) {
    return fminf(1.0f, fmaxf(-1.0f, v));
}

template<bool H>
__device__ __forceinline__ void gld8(const void* __restrict__ p, long idx, bool ok, float* o) {
    if (!ok) {
        #pragma unroll
        for (int e = 0; e < 8; ++e) o[e] = 0.f;
        return;
    }
    if constexpr (H) {
        h16x8 v = *reinterpret_cast<const h16x8*>(reinterpret_cast<const h16*>(p) + idx);
        #pragma unroll
        for (int e = 0; e < 8; ++e) o[e] = (float)v[e];
    } else {
        const float* q = reinterpret_cast<const float*>(p) + idx;
        f32x4 a = *reinterpret_cast<const f32x4*>(q);
        f32x4 b = *reinterpret_cast<const f32x4*>(q + 4);
        o[0]=a.x;o[1]=a.y;o[2]=a.z;o[3]=a.w;o[4]=b.x;o[5]=b.y;o[6]=b.z;o[7]=b.w;
    }
}

__device__ __forceinline__ void lds8h(const h16* p, float* o) {
    h16x8 v = *reinterpret_cast<const h16x8*>(p);
    #pragma unroll
    for (int e = 0; e < 8; ++e) o[e] = (float)v[e];
}
__device__ __forceinline__ void lds8f(const float* p, float* o) {
    f32x4 a = *reinterpret_cast<const f32x4*>(p);
    f32x4 b = *reinterpret_cast<const f32x4*>(p + 4);
    o[0]=a.x;o[1]=a.y;o[2]=a.z;o[3]=a.w;o[4]=b.x;o[5]=b.y;o[6]=b.z;o[7]=b.w;
}

// MODE: 0 = first (y/w/img read f32; emits w_h/img_h), 1 = mid, 2 = last.
template<int MODE, bool WH, bool IH>
__global__ __launch_bounds__(320, 4)
void pd2(const h16* __restrict__ xprev, const h16* __restrict__ xcur,
         const void* __restrict__ yin, const void* __restrict__ w,
         const void* __restrict__ img,
         h16* __restrict__ xo1, h16* __restrict__ xo2, h16* __restrict__ yo,
         h16* __restrict__ w_h, h16* __restrict__ img_h,
         float* __restrict__ out)
{
    constexpr bool FIRST = (MODE == 0);
    constexpr bool LAST  = (MODE == 2);
    constexpr bool WRH = (!FIRST) && WH;   // w reads are half
    constexpr bool IRH = (!FIRST) && IH;   // img reads are half

    __shared__ float sXT[RRW][LSW];
    __shared__ h16   sY0[RRW][LSW];
    __shared__ h16   sY1[RRW][LSW];
    __shared__ h16   sW0[RRW][LSW];
    __shared__ h16   sW1[RRW][LSW];

    const int tid = threadIdx.x;
    const int r = tid >> 4;            // 0..19
    const int s = tid & 15;            // 0..15
    const int l = 8 * s;               // local col 0..120 (tile col l-8)
    const int L = l + 8;               // LDS index of strip start
    const int gi  = blockIdx.y * TIR - 2 + r;
    const int gj0 = blockIdx.x * TIC - 8 + l;
    const long idx = (long)gi * NN + gj0;
    const bool ok = (gi >= 0) & (gi < MM) & (gj0 >= 0) & (gj0 < NN);
    const bool interior = (r >= 2) & (r <= 17) & (s >= 1) & (s <= 14) & (gj0 < NN);
    const bool notbot = gi < MM - 1;

    float xcv[8], y0v[8], y1v[8], w0v[8], w1v[8], gim[8], xtv[8];

    // ---------------- Stage 0: all global loads (single latency exposure)
    if constexpr (FIRST) {
        gld8<false>(img, idx, ok, gim);
        gld8<false>(yin, idx, ok, y0v);
        gld8<false>(yin, (long)PP + idx, ok, y1v);
        gld8<false>(w, idx, ok, w0v);
        gld8<false>(w, (long)PP + idx, ok, w1v);
        #pragma unroll
        for (int e = 0; e < 8; ++e) { xcv[e] = gim[e]; xtv[e] = gim[e]; }  // x0 = xt0 = img
    } else {
        float xpv[8];
        gld8<true>(xprev, idx, ok, xpv);
        gld8<true>(xcur,  idx, ok, xcv);
        gld8<IRH>(img, idx, ok, gim);
        gld8<true>(yin, idx, ok, y0v);
        gld8<true>(yin, (long)PP + idx, ok, y1v);
        gld8<WRH>(w, idx, ok, w0v);
        gld8<WRH>(w, (long)PP + idx, ok, w1v);
        #pragma unroll
        for (int e = 0; e < 8; ++e) xtv[e] = fmaf(THETA_F, xcv[e] - xpv[e], xcv[e]);
    }

    #pragma unroll
    for (int e = 0; e < 8; ++e) sXT[r][L + e] = xtv[e];
    {
        h16x8 t0, t1;
        #pragma unroll
        for (int e = 0; e < 8; ++e) { t0[e] = (h16)w0v[e]; t1[e] = (h16)w1v[e]; }
        *reinterpret_cast<h16x8*>(&sW0[r][L]) = t0;
        *reinterpret_cast<h16x8*>(&sW1[r][L]) = t1;
        if constexpr (FIRST && WH) {
            if (interior) {
                *reinterpret_cast<h16x8*>(&w_h[idx]) = t0;
                *reinterpret_cast<h16x8*>(&w_h[PP + idx]) = t1;
            }
        }
    }
    if constexpr (FIRST && IH) {
        if (interior) {
            h16x8 tg;
            #pragma unroll
            for (int e = 0; e < 8; ++e) tg[e] = (h16)gim[e];
            *reinterpret_cast<h16x8*>(&img_h[idx]) = tg;
        }
    }
    if (s == 0) {        // zero left pads (bounded halo garbage)
        #pragma unroll
        for (int e = 0; e < 8; ++e) { sY0[r][e] = (h16)0.f; sW0[r][e] = (h16)0.f; }
    }
    if (s == 15) {       // zero right pad of xt
        #pragma unroll
        for (int e = 0; e < 8; ++e) sXT[r][136 + e] = 0.f;
    }
    __syncthreads();

    // ---------------- Stage 1: y' for rows 0..18 (own regs + LDS neighbors)
    if (r <= 18) {
        float xtD[8];
        const float xtR = sXT[r][L + 8];
        lds8f(&sXT[r + 1][L], xtD);
        h16x8 t0, t1;
        #pragma unroll
        for (int e = 0; e < 8; ++e) {
            const float xr = (e < 7) ? xtv[e + 1] : xtR;
            const float gx = (gj0 + e < NN - 1) ? (xr - xtv[e]) : 0.f;
            const float gy = notbot ? (xtD[e] - xtv[e]) : 0.f;
            t0[e] = (h16)clip1(fmaf(SIGMA_F * gx, w0v[e], y0v[e]));
            t1[e] = (h16)clip1(fmaf(SIGMA_F * gy, w1v[e], y1v[e]));
            y0v[e] = (float)t0[e];
            y1v[e] = (float)t1[e];
        }
        *reinterpret_cast<h16x8*>(&sY0[r][L]) = t0;
        *reinterpret_cast<h16x8*>(&sY1[r][L]) = t1;
    }
    __syncthreads();

    // ---------------- Stage 2: x_{t+1} + xt_{t+1} for rows 1..18
    if (r >= 1 && r <= 18) {
        const float y0L = (float)sY0[r][L - 1];
        const float w0L = (float)sW0[r][L - 1];
        float y1U[8], w1U[8];
        lds8h(&sY1[r - 1][L], y1U);
        lds8h(&sW1[r - 1][L], w1U);
        float hh[8];
        #pragma unroll
        for (int e = 0; e < 8; ++e)
            hh[e] = (gj0 + e < NN - 1) ? w0v[e] * y0v[e] : 0.f;
        float dh[8];
        dh[0] = hh[0] - w0L * y0L;
        #pragma unroll
        for (int e = 1; e < 8; ++e) dh[e] = hh[e] - hh[e - 1];
        h16x8 xh;
        #pragma unroll
        for (int e = 0; e < 8; ++e) {
            const float vC = notbot ? w1v[e] * y1v[e] : 0.f;
            const float vU = w1U[e] * y1U[e];
            const float xv = (xcv[e] + TAU_F * (dh[e] + vC - vU) + LT_F * gim[e]) * INV_DEN;
            const h16 hx = (h16)xv;
            const float xvh = (float)hx;      // half-rounded, as unfused pipeline
            xh[e] = hx;
            xtv[e] = fmaf(THETA_F, xvh - xcv[e], xvh);
            xcv[e] = xvh;
        }
        #pragma unroll
        for (int e = 0; e < 8; ++e) sXT[r][L + e] = xtv[e];
        if constexpr (!LAST) {
            if (interior) *reinterpret_cast<h16x8*>(&xo1[idx]) = xh;
        }
    }
    __syncthreads();

    // ---------------- Stage 3: y'' for rows 1..17
    if (r >= 1 && r <= 17) {
        float xtD[8];
        const float xtR = sXT[r][L + 8];
        lds8f(&sXT[r + 1][L], xtD);
        h16x8 t0, t1;
        #pragma unroll
        for (int e = 0; e < 8; ++e) {
            const float xr = (e < 7) ? xtv[e + 1] : xtR;
            const float gx = (gj0 + e < NN - 1) ? (xr - xtv[e]) : 0.f;
            const float gy = notbot ? (xtD[e] - xtv[e]) : 0.f;
            t0[e] = (h16)clip1(fmaf(SIGMA_F * gx, w0v[e], y0v[e]));
            t1[e] = (h16)clip1(fmaf(SIGMA_F * gy, w1v[e], y1v[e]));
            y0v[e] = (float)t0[e];
            y1v[e] = (float)t1[e];
        }
        *reinterpret_cast<h16x8*>(&sY0[r][L]) = t0;
        *reinterpret_cast<h16x8*>(&sY1[r][L]) = t1;
        if constexpr (!LAST) {
            if (interior) {
                *reinterpret_cast<h16x8*>(&yo[idx]) = t0;
                *reinterpret_cast<h16x8*>(&yo[PP + idx]) = t1;
            }
        }
    }
    __syncthreads();

    // ---------------- Stage 4: x_{t+2} on the interior
    if (interior) {
        const float y0L = (float)sY0[r][L - 1];
        const float w0L = (float)sW0[r][L - 1];
        float y1U[8], w1U[8];
        lds8h(&sY1[r - 1][L], y1U);
        lds8h(&sW1[r - 1][L], w1U);
        float hh[8];
        #pragma unroll
        for (int e = 0; e < 8; ++e)
            hh[e] = (gj0 + e < NN - 1) ? w0v[e] * y0v[e] : 0.f;
        float dh[8];
        dh[0] = hh[0] - w0L * y0L;
        #pragma unroll
        for (int e = 1; e < 8; ++e) dh[e] = hh[e] - hh[e - 1];
        if constexpr (!LAST) {
            h16x8 xh;
            #pragma unroll
            for (int e = 0; e < 8; ++e) {
                const float vC = notbot ? w1v[e] * y1v[e] : 0.f;
                const float vU = w1U[e] * y1U[e];
                const float xv = (xcv[e] + TAU_F * (dh[e] + vC - vU) + LT_F * gim[e]) * INV_DEN;
                xh[e] = (h16)xv;
            }
            *reinterpret_cast<h16x8*>(&xo2[idx]) = xh;
        } else {
            float o[8];
            #pragma unroll
            for (int e = 0; e < 8; ++e) {
                const float vC = notbot ? w1v[e] * y1v[e] : 0.f;
                const float vU = w1U[e] * y1U[e];
                const float xv = (xcv[e] + TAU_F * (dh[e] + vC - vU) + LT_F * gim[e]) * INV_DEN;
                o[e] = fmaf(THETA_F, xv - xcv[e], xv);   // x_tilde_20, f32
            }
            f32x4 a, b;
            a.x = o[0]; a.y = o[1]; a.z = o[2]; a.w = o[3];
            b.x = o[4]; b.y = o[5]; b.z = o[6]; b.w = o[7];
            *reinterpret_cast<f32x4*>(&out[idx]) = a;
            *reinterpret_cast<f32x4*>(&out[idx + 4]) = b;
        }
    }
}

template<bool WH, bool IH>
static void run_seq(hipStream_t s, const float* img, const float* w, const float* y0,
                    h16* const* xb, h16* yA, h16* yB, h16* w_h, h16* img_h, float* out)
{
    const dim3 grid((NN + TIC - 1) / TIC, MM / TIR);   // 37 x 256
    const dim3 block(320);
    for (int k = 0; k < 10; ++k) {
        const h16* xp = xb[(2 * k + 3) & 3];
        const h16* xc = xb[(2 * k) & 3];
        h16* xo1 = xb[(2 * k + 1) & 3];
        h16* xo2 = xb[(2 * k + 2) & 3];
        const void* yin = (k == 0) ? (const void*)y0
                                   : ((k & 1) ? (const void*)yA : (const void*)yB);
        h16* yo = (k & 1) ? yB : yA;
        const void* wp = (k == 0) ? (const void*)w
                                  : (WH ? (const void*)w_h : (const void*)w);
        const void* ip = (k == 0) ? (const void*)img
                                  : (IH ? (const void*)img_h : (const void*)img);
        if (k == 0)
            pd2<0, WH, IH><<<grid, block, 0, s>>>(xp, xc, yin, wp, ip, xo1, xo2, yo, w_h, img_h, out);
        else if (k == 9)
            pd2<2, WH, IH><<<grid, block, 0, s>>>(xp, xc, yin, wp, ip, xo1, xo2, yo, w_h, img_h, out);
        else
            pd2<1, WH, IH><<<grid, block, 0, s>>>(xp, xc, yin, wp, ip, xo1, xo2, yo, w_h, img_h, out);
    }
}

extern "C" void kernel_launch(void* const* d_in, const int* in_sizes, int n_in,
                              void* d_out, int out_size, void* d_ws, size_t ws_size,
                              hipStream_t stream) {
    const float* img = (const float*)d_in[0];   // [1,M,N]
    const float* w   = (const float*)d_in[1];   // [2,M,N]
    const float* y0  = (const float*)d_in[2];   // [2,M,N]

    h16* base = (h16*)d_ws;
    h16* xb[4] = { base, base + PP, base + 2 * PP, base + 3 * PP };
    h16* yA = base + 4 * PP;                    // 2 planes

    const size_t planes = ws_size / (PP * sizeof(h16));
    const bool WH = planes >= 8;                          // w as half (2 planes)
    const bool IH = (planes >= 9) || (planes == 7);       // img as half (1 plane)
    h16* w_h   = WH ? base + 6 * PP : nullptr;
    h16* img_h = IH ? (WH ? base + 8 * PP : base + 6 * PP) : nullptr;

    h16* yB = (h16*)d_out;                      // 2 half planes == out_size f32 bytes
    float* out = (float*)d_out;

    if (WH && IH)      run_seq<true,  true >(stream, img, w, y0, xb, yA, yB, w_h, img_h, out);
    else if (WH)       run_seq<true,  false>(stream, img, w, y0, xb, yA, yB, w_h, img_h, out);
    else if (IH)       run_seq<false, true >(stream, img, w, y0, xb, yA, yB, w_h, img_h, out);
    else               run_seq<false, false>(stream, img, w, y0, xb, yA, yB, w_h, img_h, out);
}